// Round 1
// 130.936 us; speedup vs baseline: 1.0810x; 1.0810x over previous
//
#include <hip/hip_runtime.h>
#include <math.h>

// 192 blocks x 1024 threads, 6 per batch element (n = bid&31, r = bid>>5).
// NO atomic RMWs anywhere: all cross-block exchange is single-writer relaxed
// agent-scope atomic stores/loads, ordered by per-block release-stored MAGIC
// flags that waiters poll in parallel (one thread per flag).
// Barriers are scoped: BN1 = 32 flags (r==0 writers), BN2 = 32 same-r flags,
// head waits only on its 5 siblings. Non-head blocks store and exit.
// Head blocks hide w_rel/w_fc1 fetch latency between flag-post and flag-wait
// by computing the q-half of fc1 early (exact split: h = h_q + h_sterm).
// ws is 0xAA-poisoned before every call -> flags start != MAGIC, no memset.
//
// R1: conv2 restructured to kill its LDS-pipe serialization:
//  - y1 tile stored with +1 row / +1 col zeroed border, pitch 40 ushorts
//    (2-row lane step = +8 banks -> free 2-way alias instead of 4-way conflict)
//  - each slot (t>>8) now covers 6 INPUT channels and accumulates partials for
//    all 4 output channels (kills the 4x redundant y1 reads), taps fetched as
//    b32 pairs (ds_read2) instead of 3 scalar u16 reads
//  - cross-slot reduction through a small padded LDS buffer (2-way, free)
//  border semantics: zero ACTIVATION padding preserved by predicating
//  row==0 / col==0 lanes to 0 after bn+relu.

#define N_BATCH 32
#define C_OUT 24
#define NBLK 192
#define MAGIC 0x13579BDFu
#define AGENT __HIP_MEMORY_SCOPE_AGENT
#define PITCH 40                 // ushorts per row (row 0 and col 0 are zero border)
#define NROWS 33                 // rows 0..32 (row = oh+1)
#define CHSZ (PITCH * NROWS)     // 1320 ushorts per channel plane

__device__ __forceinline__ float aload(const float* p) {
  return __hip_atomic_load(p, __ATOMIC_RELAXED, AGENT);
}
__device__ __forceinline__ void astore(float* p, float v) {
  __hip_atomic_store(p, v, __ATOMIC_RELAXED, AGENT);
}
__device__ __forceinline__ void waitflag(const unsigned* f) {
  while (__hip_atomic_load(f, __ATOMIC_ACQUIRE, AGENT) != MAGIC)
    __builtin_amdgcn_s_sleep(1);
}

__global__ __launch_bounds__(1024) void fused_kernel(
    const float* __restrict__ img, const float* __restrict__ ques,
    const float* __restrict__ c1w, const float* __restrict__ c1b,
    const float* __restrict__ g1,  const float* __restrict__ bt1,
    const float* __restrict__ c2w, const float* __restrict__ c2b,
    const float* __restrict__ g2,  const float* __restrict__ bt2,
    const float* __restrict__ w_rel, const float* __restrict__ b_rel,
    const float* __restrict__ w_fc1, const float* __restrict__ b_fc1,
    const float* __restrict__ w_fc2, const float* __restrict__ b_fc2,
    float* __restrict__ out,
    unsigned* __restrict__ flags1, unsigned* __restrict__ flags2,
    unsigned* __restrict__ flags3,
    float* __restrict__ p1, float* __restrict__ p2,
    float* __restrict__ ssum) {
  const int t = threadIdx.x;
  const int bid = blockIdx.x;
  const int lane = t & 63, wid = t >> 6;
  const int n = bid & 31;
  const int r = bid >> 5;            // 0..5, owns channels r*4..r*4+3

  __shared__ unsigned short y1u[24 * CHSZ];   // ~61.9 KB, bf16, bordered+pitched
  __shared__ float red[5120];                 // 20 KB cross-slot reduce, pad 5
  __shared__ float s_a[C_OUT], s_b[C_OUT];    // BN1 scale/shift
  __shared__ float a2[4], b2[4];              // BN2 (this block's 4 channels)
  __shared__ float chS[16], chS2[16];
  __shared__ float qpart[1024];
  __shared__ float qfull[128];
  __shared__ float s_s[26];
  __shared__ float s_rel[128];
  __shared__ float s_h[1024];

  float h_local = 0.f;   // q-half of fc1 (head blocks only)

  // zero the borders (row 0 fully; col 0 of rows 1..32) before first use
  if (t < 24 * PITCH) {
    int ch = t / PITCH;
    y1u[ch * CHSZ + (t - ch * PITCH)] = 0;            // row 0
  }
  if (t < 768)
    y1u[(t >> 5) * CHSZ + ((t & 31) + 1) * PITCH] = 0; // col 0, rows 1..32

  // ---------------- phase 1: conv1, 1 pixel/thread, all 24 co ----------------
  {
    int oh = t >> 5, ow = t & 31;
    float win[27];
    #pragma unroll
    for (int ci = 0; ci < 3; ci++)
      #pragma unroll
      for (int kh = 0; kh < 3; kh++) {
        int ih = oh * 2 - 1 + kh;
        #pragma unroll
        for (int kw = 0; kw < 3; kw++) {
          int iw = ow * 2 - 1 + kw;
          win[ci * 9 + kh * 3 + kw] =
              (ih >= 0 && iw >= 0) ? img[(n * 3 + ci) * 4096 + ih * 64 + iw] : 0.f;
        }
      }
    #pragma unroll
    for (int co = 0; co < C_OUT; co++) {
      float acc = c1b[co];
      #pragma unroll
      for (int q = 0; q < 27; q++) acc += win[q] * c1w[co * 27 + q];
      unsigned bits = __float_as_uint(acc);
      unsigned rr = (bits + 0x7FFFu + ((bits >> 16) & 1u)) >> 16;  // rne
      y1u[co * CHSZ + (oh + 1) * PITCH + (ow + 1)] = (unsigned short)rr;
    }
  }
  __syncthreads();

  // stage-1 stats: only r==0 blocks write p1 + flags1[n]
  if (r == 0) {
    if (t < 768) {
      int ch = t >> 5, l = t & 31;
      float s = 0.f, s2 = 0.f;
      #pragma unroll
      for (int i = 0; i < 32; i++) {
        float x = __uint_as_float(
            (unsigned)y1u[ch * CHSZ + (i + 1) * PITCH + (l + 1)] << 16);
        s += x; s2 += x * x;
      }
      #pragma unroll
      for (int off = 16; off > 0; off >>= 1) {
        s += __shfl_down(s, off, 32);
        s2 += __shfl_down(s2, off, 32);
      }
      if (l == 0) {
        astore(&p1[ch * 32 + n], s);
        astore(&p1[768 + ch * 32 + n], s2);
      }
    }
    __syncthreads();
    if (t == 0)
      __hip_atomic_store(&flags1[n], MAGIC, __ATOMIC_RELEASE, AGENT);
  }

  // ---------------- wait BN1 stats + finalize (all blocks) ----------------
  if (t < 32) waitflag(&flags1[t]);
  __syncthreads();
  if (t < 768) {
    int ch = t >> 5, j = t & 31;
    float s = aload(&p1[ch * 32 + j]);
    float s2 = aload(&p1[768 + ch * 32 + j]);
    #pragma unroll
    for (int off = 16; off > 0; off >>= 1) {
      s += __shfl_down(s, off, 32);
      s2 += __shfl_down(s2, off, 32);
    }
    if (j == 0) {
      float mu = s * (1.f / 32768.f);
      float var = s2 * (1.f / 32768.f) - mu * mu;
      float a = rsqrtf(var + 1e-5f) * g1[ch];
      s_a[ch] = a;
      s_b[ch] = bt1[ch] - mu * a;
    }
  }
  __syncthreads();

  // ---------------- phase 2: conv2 ----------------
  // slot = t>>8 covers INPUT channels slot*6..slot*6+5 and accumulates
  // partials for ALL 4 output channels of this block; y1 taps fetched as
  // b32 pairs (4x fewer bytes-touched than the old per-co scheme, ~6x fewer
  // LDS instructions, conflict-free).
  const int px = t & 255;
  const int slot = t >> 8;                         // 0..3, wave-uniform
  const int co2 = r * 4 + slot;
  float acc2;
  {
    const int o2h = px >> 4, o2w = px & 15;
    float accq[4] = {0.f, 0.f, 0.f, 0.f};
    const int ci0 = slot * 6;
    #pragma unroll
    for (int cc = 0; cc < 6; cc++) {
      const int ci = ci0 + cc;
      const float a1 = s_a[ci], b1 = s_b[ci];
      const unsigned* chp = (const unsigned*)(y1u + ci * CHSZ);
      #pragma unroll
      for (int kh = 0; kh < 3; kh++) {
        const int row = o2h * 2 + kh;              // = ih+1, in 0..32
        const unsigned* pr = chp + row * (PITCH / 2);
        unsigned w0 = pr[o2w];                     // cols 2*o2w, 2*o2w+1
        unsigned w1 = pr[o2w + 1];                 // cols 2*o2w+2, (+3 unused)
        float x0 = __uint_as_float(w0 << 16);
        float x1 = __uint_as_float(w0 & 0xffff0000u);
        float x2 = __uint_as_float(w1 << 16);
        x0 = fmaxf(fmaf(x0, a1, b1), 0.f);
        x1 = fmaxf(fmaf(x1, a1, b1), 0.f);
        x2 = fmaxf(fmaf(x2, a1, b1), 0.f);
        if (row == 0) { x0 = 0.f; x1 = 0.f; x2 = 0.f; }  // top zero-pad
        if (o2w == 0) x0 = 0.f;                           // left zero-pad
        #pragma unroll
        for (int co = 0; co < 4; co++) {
          const float* wp = c2w + ((r * 4 + co) * C_OUT + ci) * 9 + kh * 3;
          accq[co] = fmaf(x0, wp[0], accq[co]);
          accq[co] = fmaf(x1, wp[1], accq[co]);
          accq[co] = fmaf(x2, wp[2], accq[co]);
        }
      }
    }
    // cross-slot reduce: red[(s*256+px)*5 + q], pad 5 -> 2-way free
    #pragma unroll
    for (int q = 0; q < 4; q++) red[(slot * 256 + px) * 5 + q] = accq[q];
  }
  __syncthreads();
  {
    acc2 = c2b[co2];
    #pragma unroll
    for (int s = 0; s < 4; s++) acc2 += red[(s * 256 + px) * 5 + slot];
  }
  // per-block stage-2 partials (this n, 4 channels), single-writer
  {
    float s = acc2, s2 = acc2 * acc2;
    #pragma unroll
    for (int off = 32; off > 0; off >>= 1) {
      s += __shfl_down(s, off, 64);
      s2 += __shfl_down(s2, off, 64);
    }
    if (lane == 0) { chS[slot * 4 + (wid & 3)] = s; chS2[slot * 4 + (wid & 3)] = s2; }
  }
  __syncthreads();
  if (t < 4) {
    float s = chS[t * 4] + chS[t * 4 + 1] + chS[t * 4 + 2] + chS[t * 4 + 3];
    float s2 = chS2[t * 4] + chS2[t * 4 + 1] + chS2[t * 4 + 2] + chS2[t * 4 + 3];
    astore(&p2[(r * 4 + t) * 32 + n], s);
    astore(&p2[768 + (r * 4 + t) * 32 + n], s2);
  }
  __syncthreads();
  if (t == 0)
    __hip_atomic_store(&flags2[bid], MAGIC, __ATOMIC_RELEASE, AGENT);

  // ---------------- head blocks: hide q-term + fc1 q-half here ----------------
  if (r == 0) {
    {
      int m = t & 127, g = t >> 7;
      const float* qv = ques + n * 128;
      float q = 0.f;
      for (int k = g * 16; k < g * 16 + 16; k++)
        q += qv[k] * w_rel[(52 + k) * 128 + m];
      qpart[t] = q;
    }
    __syncthreads();
    if (t < 128) {
      float q = b_rel[t];
      #pragma unroll
      for (int g = 0; g < 8; g++) q += qpart[g * 128 + t];
      qfull[t] = 65536.f * q;
    }
    __syncthreads();
    {
      float hl = b_fc1[t];
      #pragma unroll 8
      for (int m = 0; m < 128; m++) hl += qfull[m] * w_fc1[m * 1024 + t];
      h_local = hl;          // also warms L2 for the sterm pass
    }
  }

  // ---------------- wait BN2 stats for our r-group, finalize 4 channels -------
  if (t < 32) waitflag(&flags2[r * 32 + t]);
  __syncthreads();
  if (t < 128) {
    int c4 = t >> 5, j = t & 31;
    float s = aload(&p2[(r * 4 + c4) * 32 + j]);
    float s2 = aload(&p2[768 + (r * 4 + c4) * 32 + j]);
    #pragma unroll
    for (int off = 16; off > 0; off >>= 1) {
      s += __shfl_down(s, off, 32);
      s2 += __shfl_down(s2, off, 32);
    }
    if (j == 0) {
      float mu = s * (1.f / 8192.f);
      float var = s2 * (1.f / 8192.f) - mu * mu;
      float a = rsqrtf(var + 1e-5f) * g2[r * 4 + c4];
      a2[c4] = a;
      b2[c4] = bt2[r * 4 + c4] - mu * a;
    }
  }
  __syncthreads();

  // relu(bn2) spatial sums -> ssum[n*24+co], single-writer
  {
    float v = acc2 * a2[slot] + b2[slot];
    v = v > 0.f ? v : 0.f;
    #pragma unroll
    for (int off = 32; off > 0; off >>= 1) v += __shfl_down(v, off, 64);
    if (lane == 0) chS[slot * 4 + (wid & 3)] = v;
  }
  __syncthreads();
  if (t < 4)
    astore(&ssum[n * C_OUT + r * 4 + t],
           chS[t * 4] + chS[t * 4 + 1] + chS[t * 4 + 2] + chS[t * 4 + 3]);
  __syncthreads();
  if (t == 0)
    __hip_atomic_store(&flags3[bid], MAGIC, __ATOMIC_RELEASE, AGENT);

  if (r != 0) return;   // non-head blocks never wait past here

  // ---------------- phase 3: head (32 blocks), wait 5 siblings only ----------
  if (t >= 1 && t < 6) waitflag(&flags3[t * 32 + n]);
  __syncthreads();
  if (t < C_OUT) s_s[t] = aload(&ssum[n * C_OUT + t]);
  if (t == 24 || t == 25) {
    float cs = 0.f;
    for (int i = 0; i < 16; i++) cs += -1.f + 2.f * (float)i / 15.f;
    s_s[t] = 16.f * cs;
  }
  __syncthreads();
  if (t < 128) {
    float sterm = 0.f;
    #pragma unroll
    for (int d = 0; d < 26; d++)
      sterm += s_s[d] * (w_rel[d * 128 + t] + w_rel[(26 + d) * 128 + t]);
    s_rel[t] = 256.f * sterm;
  }
  __syncthreads();

  // fc1 sterm-half (w_fc1 now L2-warm) + relu
  {
    float acc = h_local;
    #pragma unroll 8
    for (int m = 0; m < 128; m++) acc += s_rel[m] * w_fc1[m * 1024 + t];
    s_h[t] = acc > 0.f ? acc : 0.f;
  }
  __syncthreads();

  // fc2
  {
    float hv = s_h[t];
    float a0 = hv * w_fc2[2 * t], a1 = hv * w_fc2[2 * t + 1];
    #pragma unroll
    for (int off = 32; off > 0; off >>= 1) {
      a0 += __shfl_down(a0, off, 64);
      a1 += __shfl_down(a1, off, 64);
    }
    if (lane == 0) { chS[wid] = a0; chS2[wid] = a1; }
  }
  __syncthreads();
  if (t == 0) {
    float a0 = 0.f, a1 = 0.f;
    #pragma unroll
    for (int i = 0; i < 16; i++) { a0 += chS[i]; a1 += chS2[i]; }
    out[n * 2 + 0] = a0 + b_fc2[0];
    out[n * 2 + 1] = a1 + b_fc2[1];
  }
}

extern "C" void kernel_launch(void* const* d_in, const int* in_sizes, int n_in,
                              void* d_out, int out_size, void* d_ws, size_t ws_size,
                              hipStream_t stream) {
  const float* image   = (const float*)d_in[0];
  const float* ques    = (const float*)d_in[1];
  const float* conv1_w = (const float*)d_in[2];
  const float* conv1_b = (const float*)d_in[3];
  const float* bn1_g   = (const float*)d_in[4];
  const float* bn1_b   = (const float*)d_in[5];
  const float* conv2_w = (const float*)d_in[6];
  const float* conv2_b = (const float*)d_in[7];
  const float* bn2_g   = (const float*)d_in[8];
  const float* bn2_b   = (const float*)d_in[9];
  const float* w_rel   = (const float*)d_in[10];
  const float* b_rel   = (const float*)d_in[11];
  const float* w_fc1   = (const float*)d_in[12];
  const float* b_fc1   = (const float*)d_in[13];
  const float* w_fc2   = (const float*)d_in[14];
  const float* b_fc2   = (const float*)d_in[15];
  float* out = (float*)d_out;

  unsigned* flags1 = (unsigned*)d_ws;          // 32
  unsigned* flags2 = flags1 + 32;              // 192
  unsigned* flags3 = flags2 + 192;             // 192  (total 416 uints)
  float* p1   = (float*)d_ws + 416;            // 1536
  float* p2   = p1 + 1536;                     // 1536
  float* ssum = p2 + 1536;                     // 768

  fused_kernel<<<NBLK, 1024, 0, stream>>>(
      image, ques, conv1_w, conv1_b, bn1_g, bn1_b, conv2_w, conv2_b,
      bn2_g, bn2_b, w_rel, b_rel, w_fc1, b_fc1, w_fc2, b_fc2,
      out, flags1, flags2, flags3, p1, p2, ssum);
}

// Round 2
// 120.709 us; speedup vs baseline: 1.1726x; 1.0847x over previous
//
#include <hip/hip_runtime.h>
#include <math.h>

// 192 blocks x 1024 threads, 6 per batch element (n = bid&31, r = bid>>5).
// NO atomic RMWs anywhere: all cross-block exchange is single-writer relaxed
// agent-scope atomic stores/loads, ordered by per-block release-stored MAGIC
// flags. R2: flag polls are RELAXED (no per-poll buffer_inv). Safe because all
// cross-block data (p1/p2/ssum) is read via relaxed agent atomic loads that
// bypass the non-coherent caches, and every ordinary cached global read after
// a wait (weights) is iteration-invariant.
// Barriers are scoped: BN1 = 32 flags (r==0 writers), BN2 = 32 same-r flags,
// head waits only on its 5 siblings. Non-head blocks store and exit.
//
// R1: conv2 restructured (bordered pitch-40 bf16 tile, slot=input-channel
// split, b32 pair reads, cross-slot LDS reduce) -> bank conflicts 829K->235K.
// R2: tail compression (occupancy math showed ~half the runtime is the
// 32-head-block tail):
//  - detour's fc1 q-half pass DELETED (it was serial on the head's path and
//    hid nothing); replaced by a 4-loads/thread L2 prefetch of w_fc1 (1 dword
//    per 128B line) + w_rel/w_fc2/b_fc1 prefetch + the cheap qfull compute.
//  - phase 3 computes ONE fused fc1 pass over coef[m]=qfull[m]+256*sterm[m],
//    float4 loads, mg-split (32 x float4 per thread, 1KiB/wave coalesced),
//    LDS reduce, then fc2.
//  - s_rel partials spread over all 1024 threads (was 128).

#define N_BATCH 32
#define C_OUT 24
#define NBLK 192
#define MAGIC 0x13579BDFu
#define AGENT __HIP_MEMORY_SCOPE_AGENT
#define PITCH 40                 // ushorts per row (row 0 and col 0 are zero border)
#define NROWS 33                 // rows 0..32 (row = oh+1)
#define CHSZ (PITCH * NROWS)     // 1320 ushorts per channel plane

__device__ __forceinline__ float aload(const float* p) {
  return __hip_atomic_load(p, __ATOMIC_RELAXED, AGENT);
}
__device__ __forceinline__ void astore(float* p, float v) {
  __hip_atomic_store(p, v, __ATOMIC_RELAXED, AGENT);
}
__device__ __forceinline__ void waitflag(const unsigned* f) {
  // RELAXED poll: agent-scope atomic load bypasses non-coherent L1/L2 each
  // iteration (read-through to coherence point), no buffer_inv per poll.
  while (__hip_atomic_load(f, __ATOMIC_RELAXED, AGENT) != MAGIC)
    __builtin_amdgcn_s_sleep(1);
}

__global__ __launch_bounds__(1024) void fused_kernel(
    const float* __restrict__ img, const float* __restrict__ ques,
    const float* __restrict__ c1w, const float* __restrict__ c1b,
    const float* __restrict__ g1,  const float* __restrict__ bt1,
    const float* __restrict__ c2w, const float* __restrict__ c2b,
    const float* __restrict__ g2,  const float* __restrict__ bt2,
    const float* __restrict__ w_rel, const float* __restrict__ b_rel,
    const float* __restrict__ w_fc1, const float* __restrict__ b_fc1,
    const float* __restrict__ w_fc2, const float* __restrict__ b_fc2,
    float* __restrict__ out,
    unsigned* __restrict__ flags1, unsigned* __restrict__ flags2,
    unsigned* __restrict__ flags3,
    float* __restrict__ p1, float* __restrict__ p2,
    float* __restrict__ ssum) {
  const int t = threadIdx.x;
  const int bid = blockIdx.x;
  const int lane = t & 63, wid = t >> 6;
  const int n = bid & 31;
  const int r = bid >> 5;            // 0..5, owns channels r*4..r*4+3

  __shared__ unsigned short y1u[24 * CHSZ];   // ~61.9 KB, bf16, bordered+pitched
  __shared__ float red[5120];                 // conv2 reduce (x5) / fc1 reduce (x17)
  __shared__ float s_a[C_OUT], s_b[C_OUT];    // BN1 scale/shift
  __shared__ float a2[4], b2[4];              // BN2 (this block's 4 channels)
  __shared__ float chS[16], chS2[16];
  __shared__ float qpart[1024];
  __shared__ float qfull[128];
  __shared__ float s_s[26];
  __shared__ float s_coef[128];
  __shared__ float s_h[1024];

  // zero the borders (row 0 fully; col 0 of rows 1..32) before first use
  if (t < 24 * PITCH) {
    int ch = t / PITCH;
    y1u[ch * CHSZ + (t - ch * PITCH)] = 0;            // row 0
  }
  if (t < 768)
    y1u[(t >> 5) * CHSZ + ((t & 31) + 1) * PITCH] = 0; // col 0, rows 1..32

  // ---------------- phase 1: conv1, 1 pixel/thread, all 24 co ----------------
  {
    int oh = t >> 5, ow = t & 31;
    float win[27];
    #pragma unroll
    for (int ci = 0; ci < 3; ci++)
      #pragma unroll
      for (int kh = 0; kh < 3; kh++) {
        int ih = oh * 2 - 1 + kh;
        #pragma unroll
        for (int kw = 0; kw < 3; kw++) {
          int iw = ow * 2 - 1 + kw;
          win[ci * 9 + kh * 3 + kw] =
              (ih >= 0 && iw >= 0) ? img[(n * 3 + ci) * 4096 + ih * 64 + iw] : 0.f;
        }
      }
    #pragma unroll
    for (int co = 0; co < C_OUT; co++) {
      float acc = c1b[co];
      #pragma unroll
      for (int q = 0; q < 27; q++) acc += win[q] * c1w[co * 27 + q];
      unsigned bits = __float_as_uint(acc);
      unsigned rr = (bits + 0x7FFFu + ((bits >> 16) & 1u)) >> 16;  // rne
      y1u[co * CHSZ + (oh + 1) * PITCH + (ow + 1)] = (unsigned short)rr;
    }
  }
  __syncthreads();

  // stage-1 stats: only r==0 blocks write p1 + flags1[n]
  if (r == 0) {
    if (t < 768) {
      int ch = t >> 5, l = t & 31;
      float s = 0.f, s2 = 0.f;
      #pragma unroll
      for (int i = 0; i < 32; i++) {
        float x = __uint_as_float(
            (unsigned)y1u[ch * CHSZ + (i + 1) * PITCH + (l + 1)] << 16);
        s += x; s2 += x * x;
      }
      #pragma unroll
      for (int off = 16; off > 0; off >>= 1) {
        s += __shfl_down(s, off, 32);
        s2 += __shfl_down(s2, off, 32);
      }
      if (l == 0) {
        astore(&p1[ch * 32 + n], s);
        astore(&p1[768 + ch * 32 + n], s2);
      }
    }
    __syncthreads();
    if (t == 0)
      __hip_atomic_store(&flags1[n], MAGIC, __ATOMIC_RELEASE, AGENT);
  }

  // ---------------- wait BN1 stats + finalize (all blocks) ----------------
  if (t < 32) waitflag(&flags1[t]);
  __syncthreads();
  if (t < 768) {
    int ch = t >> 5, j = t & 31;
    float s = aload(&p1[ch * 32 + j]);
    float s2 = aload(&p1[768 + ch * 32 + j]);
    #pragma unroll
    for (int off = 16; off > 0; off >>= 1) {
      s += __shfl_down(s, off, 32);
      s2 += __shfl_down(s2, off, 32);
    }
    if (j == 0) {
      float mu = s * (1.f / 32768.f);
      float var = s2 * (1.f / 32768.f) - mu * mu;
      float a = rsqrtf(var + 1e-5f) * g1[ch];
      s_a[ch] = a;
      s_b[ch] = bt1[ch] - mu * a;
    }
  }
  __syncthreads();

  // ---------------- phase 2: conv2 ----------------
  const int px = t & 255;
  const int slot = t >> 8;                         // 0..3, wave-uniform
  const int co2 = r * 4 + slot;
  float acc2;
  {
    const int o2h = px >> 4, o2w = px & 15;
    float accq[4] = {0.f, 0.f, 0.f, 0.f};
    const int ci0 = slot * 6;
    #pragma unroll
    for (int cc = 0; cc < 6; cc++) {
      const int ci = ci0 + cc;
      const float a1 = s_a[ci], b1 = s_b[ci];
      const unsigned* chp = (const unsigned*)(y1u + ci * CHSZ);
      #pragma unroll
      for (int kh = 0; kh < 3; kh++) {
        const int row = o2h * 2 + kh;              // = ih+1, in 0..32
        const unsigned* pr = chp + row * (PITCH / 2);
        unsigned w0 = pr[o2w];                     // cols 2*o2w, 2*o2w+1
        unsigned w1 = pr[o2w + 1];                 // cols 2*o2w+2
        float x0 = __uint_as_float(w0 << 16);
        float x1 = __uint_as_float(w0 & 0xffff0000u);
        float x2 = __uint_as_float(w1 << 16);
        x0 = fmaxf(fmaf(x0, a1, b1), 0.f);
        x1 = fmaxf(fmaf(x1, a1, b1), 0.f);
        x2 = fmaxf(fmaf(x2, a1, b1), 0.f);
        if (row == 0) { x0 = 0.f; x1 = 0.f; x2 = 0.f; }  // top zero-pad
        if (o2w == 0) x0 = 0.f;                           // left zero-pad
        #pragma unroll
        for (int co = 0; co < 4; co++) {
          const float* wp = c2w + ((r * 4 + co) * C_OUT + ci) * 9 + kh * 3;
          accq[co] = fmaf(x0, wp[0], accq[co]);
          accq[co] = fmaf(x1, wp[1], accq[co]);
          accq[co] = fmaf(x2, wp[2], accq[co]);
        }
      }
    }
    #pragma unroll
    for (int q = 0; q < 4; q++) red[(slot * 256 + px) * 5 + q] = accq[q];
  }
  __syncthreads();
  {
    acc2 = c2b[co2];
    #pragma unroll
    for (int s = 0; s < 4; s++) acc2 += red[(s * 256 + px) * 5 + slot];
  }
  // per-block stage-2 partials (this n, 4 channels), single-writer
  {
    float s = acc2, s2 = acc2 * acc2;
    #pragma unroll
    for (int off = 32; off > 0; off >>= 1) {
      s += __shfl_down(s, off, 64);
      s2 += __shfl_down(s2, off, 64);
    }
    if (lane == 0) { chS[slot * 4 + (wid & 3)] = s; chS2[slot * 4 + (wid & 3)] = s2; }
  }
  __syncthreads();
  if (t < 4) {
    float s = chS[t * 4] + chS[t * 4 + 1] + chS[t * 4 + 2] + chS[t * 4 + 3];
    float s2 = chS2[t * 4] + chS2[t * 4 + 1] + chS2[t * 4 + 2] + chS2[t * 4 + 3];
    astore(&p2[(r * 4 + t) * 32 + n], s);
    astore(&p2[768 + (r * 4 + t) * 32 + n], s2);
  }
  __syncthreads();
  if (t == 0)
    __hip_atomic_store(&flags2[bid], MAGIC, __ATOMIC_RELEASE, AGENT);

  // ---- head blocks: L2 prefetch (w_fc1/w_rel/w_fc2/b_fc1) + qfull here ----
  if (r == 0) {
    {
      // one dword per 128B cache line: w_fc1 512KB = 4096 lines, 4/thread
      float pf = 0.f;
      #pragma unroll
      for (int i = 0; i < 4; i++) pf += w_fc1[(t + i * 1024) * 32];
      if (t < 208) pf += w_rel[t * 32];     // sterm region: 52*128 floats
      if (t < 64)  pf += w_fc2[t * 32];     // 8 KB
      if (t < 32)  pf += b_fc1[t * 32];     // 4 KB
      asm volatile("" :: "v"(pf));          // keep loads alive
    }
    {
      int m = t & 127, g = t >> 7;
      const float* qv = ques + n * 128;
      float q = 0.f;
      for (int k = g * 16; k < g * 16 + 16; k++)
        q += qv[k] * w_rel[(52 + k) * 128 + m];
      qpart[t] = q;
    }
    __syncthreads();
    if (t < 128) {
      float q = b_rel[t];
      #pragma unroll
      for (int g = 0; g < 8; g++) q += qpart[g * 128 + t];
      qfull[t] = 65536.f * q;
    }
  }

  // ---------------- wait BN2 stats for our r-group, finalize 4 channels -------
  if (t < 32) waitflag(&flags2[r * 32 + t]);
  __syncthreads();
  if (t < 128) {
    int c4 = t >> 5, j = t & 31;
    float s = aload(&p2[(r * 4 + c4) * 32 + j]);
    float s2 = aload(&p2[768 + (r * 4 + c4) * 32 + j]);
    #pragma unroll
    for (int off = 16; off > 0; off >>= 1) {
      s += __shfl_down(s, off, 32);
      s2 += __shfl_down(s2, off, 32);
    }
    if (j == 0) {
      float mu = s * (1.f / 8192.f);
      float var = s2 * (1.f / 8192.f) - mu * mu;
      float a = rsqrtf(var + 1e-5f) * g2[r * 4 + c4];
      a2[c4] = a;
      b2[c4] = bt2[r * 4 + c4] - mu * a;
    }
  }
  __syncthreads();

  // relu(bn2) spatial sums -> ssum[n*24+co], single-writer
  {
    float v = acc2 * a2[slot] + b2[slot];
    v = v > 0.f ? v : 0.f;
    #pragma unroll
    for (int off = 32; off > 0; off >>= 1) v += __shfl_down(v, off, 64);
    if (lane == 0) chS[slot * 4 + (wid & 3)] = v;
  }
  __syncthreads();
  if (t < 4)
    astore(&ssum[n * C_OUT + r * 4 + t],
           chS[t * 4] + chS[t * 4 + 1] + chS[t * 4 + 2] + chS[t * 4 + 3]);
  __syncthreads();
  if (t == 0)
    __hip_atomic_store(&flags3[bid], MAGIC, __ATOMIC_RELEASE, AGENT);

  if (r != 0) return;   // non-head blocks never wait past here

  // ---------------- phase 3: head (32 blocks), wait 5 siblings only ----------
  if (t >= 1 && t < 6) waitflag(&flags3[t * 32 + n]);
  __syncthreads();
  if (t < C_OUT) s_s[t] = aload(&ssum[n * C_OUT + t]);
  if (t == 24 || t == 25) {
    float cs = 0.f;
    for (int i = 0; i < 16; i++) cs += -1.f + 2.f * (float)i / 15.f;
    s_s[t] = 16.f * cs;
  }
  __syncthreads();

  // sterm partials across all 1024 threads: col = t&127, d-range by g = t>>7
  {
    int col = t & 127, g = t >> 7;
    float p = 0.f;
    #pragma unroll
    for (int dd = 0; dd < 4; dd++) {
      int d = g + dd * 8;
      if (d < 26)
        p += s_s[d] * (w_rel[d * 128 + col] + w_rel[(26 + d) * 128 + col]);
    }
    qpart[t] = p;
  }
  __syncthreads();
  if (t < 128) {
    float sterm = 0.f;
    #pragma unroll
    for (int g = 0; g < 8; g++) sterm += qpart[g * 128 + t];
    s_coef[t] = qfull[t] + 256.f * sterm;
  }
  __syncthreads();

  // fused fc1: coef @ w_fc1, float4 loads, mg-split (m-range per wave group)
  {
    const int cg = t & 255, mg = t >> 8;          // cols 4cg..4cg+3, m mg*32..+31
    const float4* wp = (const float4*)(w_fc1) + mg * 32 * 256 + cg;
    float4 acc = make_float4(0.f, 0.f, 0.f, 0.f);
    #pragma unroll 8
    for (int k = 0; k < 32; k++) {
      float c = s_coef[mg * 32 + k];
      float4 w = wp[k * 256];
      acc.x += c * w.x; acc.y += c * w.y; acc.z += c * w.z; acc.w += c * w.w;
    }
    red[cg * 17 + mg * 4 + 0] = acc.x;
    red[cg * 17 + mg * 4 + 1] = acc.y;
    red[cg * 17 + mg * 4 + 2] = acc.z;
    red[cg * 17 + mg * 4 + 3] = acc.w;
  }
  __syncthreads();
  {
    float h = b_fc1[t];
    #pragma unroll
    for (int mg = 0; mg < 4; mg++) h += red[(t >> 2) * 17 + mg * 4 + (t & 3)];
    s_h[t] = h > 0.f ? h : 0.f;
  }
  __syncthreads();

  // fc2
  {
    float hv = s_h[t];
    float a0 = hv * w_fc2[2 * t], a1 = hv * w_fc2[2 * t + 1];
    #pragma unroll
    for (int off = 32; off > 0; off >>= 1) {
      a0 += __shfl_down(a0, off, 64);
      a1 += __shfl_down(a1, off, 64);
    }
    if (lane == 0) { chS[wid] = a0; chS2[wid] = a1; }
  }
  __syncthreads();
  if (t == 0) {
    float a0 = 0.f, a1 = 0.f;
    #pragma unroll
    for (int i = 0; i < 16; i++) { a0 += chS[i]; a1 += chS2[i]; }
    out[n * 2 + 0] = a0 + b_fc2[0];
    out[n * 2 + 1] = a1 + b_fc2[1];
  }
}

extern "C" void kernel_launch(void* const* d_in, const int* in_sizes, int n_in,
                              void* d_out, int out_size, void* d_ws, size_t ws_size,
                              hipStream_t stream) {
  const float* image   = (const float*)d_in[0];
  const float* ques    = (const float*)d_in[1];
  const float* conv1_w = (const float*)d_in[2];
  const float* conv1_b = (const float*)d_in[3];
  const float* bn1_g   = (const float*)d_in[4];
  const float* bn1_b   = (const float*)d_in[5];
  const float* conv2_w = (const float*)d_in[6];
  const float* conv2_b = (const float*)d_in[7];
  const float* bn2_g   = (const float*)d_in[8];
  const float* bn2_b   = (const float*)d_in[9];
  const float* w_rel   = (const float*)d_in[10];
  const float* b_rel   = (const float*)d_in[11];
  const float* w_fc1   = (const float*)d_in[12];
  const float* b_fc1   = (const float*)d_in[13];
  const float* w_fc2   = (const float*)d_in[14];
  const float* b_fc2   = (const float*)d_in[15];
  float* out = (float*)d_out;

  unsigned* flags1 = (unsigned*)d_ws;          // 32
  unsigned* flags2 = flags1 + 32;              // 192
  unsigned* flags3 = flags2 + 192;             // 192  (total 416 uints)
  float* p1   = (float*)d_ws + 416;            // 1536
  float* p2   = p1 + 1536;                     // 1536
  float* ssum = p2 + 1536;                     // 768

  fused_kernel<<<NBLK, 1024, 0, stream>>>(
      image, ques, conv1_w, conv1_b, bn1_g, bn1_b, conv2_w, conv2_b,
      bn2_g, bn2_b, w_rel, b_rel, w_fc1, b_fc1, w_fc2, b_fc2,
      out, flags1, flags2, flags3, p1, p2, ssum);
}